// Round 9
// baseline (404.747 us; speedup 1.0000x reference)
//
#include <hip/hip_runtime.h>
#include <hip/hip_bf16.h>

#define TRAJ 50

typedef __attribute__((ext_vector_type(8))) short short8;
typedef __attribute__((ext_vector_type(4))) float f32x4;
typedef __attribute__((ext_vector_type(2))) float f32x2;

#if defined(__has_builtin)
#if __has_builtin(__builtin_amdgcn_exp2f)
#define EXP2F(x) __builtin_amdgcn_exp2f(x)
#else
#define EXP2F(x) exp2f(x)
#endif
#if __has_builtin(__builtin_amdgcn_rcpf)
#define RCPF(x) __builtin_amdgcn_rcpf(x)
#else
#define RCPF(x) (1.0f/(x))
#endif
#else
#define EXP2F(x) exp2f(x)
#define RCPF(x) (1.0f/(x))
#endif

// LDS-only fused barrier (verified rounds 6/8): no schedulable gap between the
// lgkm wait and s_barrier; does NOT drain global stores (vmcnt).
#define BAR() asm volatile("s_waitcnt lgkmcnt(0)\n\ts_barrier" ::: "memory")

__device__ __forceinline__ unsigned short f2bf(float f){
  union { float f; unsigned u; } v; v.f = f;
  unsigned u = v.u;
  u += 0x7FFFu + ((u >> 16) & 1u);   // RNE
  return (unsigned short)(u >> 16);
}
__device__ __forceinline__ unsigned pk(unsigned short a, unsigned short b){
  return (unsigned)a | ((unsigned)b << 16);
}
__device__ __forceinline__ unsigned pkbf(float a, float b){
  union { __hip_bfloat162 h; unsigned u; } c;
  c.h = __float22bfloat162_rn(make_float2(a, b));   // v_cvt_pk_bf16_f32
  return c.u;
}
__device__ __forceinline__ short8 mkfrag(uint2 v){
  union { unsigned u[4]; short8 s; } c;
  c.u[0] = v.x; c.u[1] = v.y; c.u[2] = 0u; c.u[3] = 0u;
  return c.s;
}

#define MFMA16(A,B,C) __builtin_amdgcn_mfma_f32_16x16x32_bf16((A),(B),(C),0,0,0)

#define SSC (-1.44269504f)   // sigmoid scale: sigma(x) = 1/(1+2^(SSC*x))
#define TSC ( 2.88539008f)   // tanh scale:   tanh(y)  = 1-2/(1+2^(TSC*y))

__device__ __forceinline__ f32x2 exp2v(f32x2 v){ return (f32x2){EXP2F(v[0]), EXP2F(v[1])}; }
__device__ __forceinline__ f32x2 rcpv (f32x2 v){ return (f32x2){RCPF(v[0]), RCPF(v[1])}; }

// per element pair: r/u sigmoids share one rcp; tanh via exp2+rcp.
// (round-2/6/8 math, verified absmax 0.125)
__device__ __forceinline__ f32x2 gru_pair(f32x2 r_, f32x2 u_, f32x2 n_, f32x2 i_, f32x2 hp){
  const f32x2 one = (f32x2){1.f, 1.f};
  f32x2 d1 = exp2v(r_) + one;
  f32x2 d2 = exp2v(u_) + one;
  f32x2 rp = rcpv(d1 * d2);
  f32x2 rv = d2 * rp;                               // sigma(arg_r)
  f32x2 uv = d1 * rp;                               // sigma(arg_u)
  f32x2 y  = __builtin_elementwise_fma(rv, n_, i_); // TSC*(inn + r*hn)
  f32x2 nv = one - 2.f * rcpv(exp2v(y) + one);      // tanh
  return __builtin_elementwise_fma(uv, hp - nv, nv);
}

// gather an A fragment directly from a global row-major [K][N] f32 matrix:
// frag elements = scale * M[k0+j][i], j=0..7 (k0 = kb*32 + lg*8), i = row index.
// Proven (r7/r8): lane holds k-elems lg*8..lg*8+7 of its 32-k block.
__device__ __forceinline__ short8 gatherA(const float* __restrict__ M, int N,
                                          int k0, int i, float scale){
  const float* qp = M + (size_t)k0 * N + i;
  union { unsigned u[4]; short8 s; } c;
  #pragma unroll
  for (int j = 0; j < 4; ++j){
    float a = qp[(2*j  ) * N];
    float b = qp[(2*j+1) * N];
    c.u[j] = pk(f2bf(scale * a), f2bf(scale * b));
  }
  return c.s;
}

// DECORRELATED QUAD-SPLIT: block = 256 threads = 4 waves = ONE 16-row group.
// Each wave owns 16 of the 64 gate dims (q = dim quarter). h exchanged via
// double-buffered LDS (4KB/block), one fused LDS barrier per step — barrier
// scope is exactly the 4 cooperating waves, so independent blocks drift out
// of phase and fill each other's pipe bubbles on a shared SIMD.
// Weights gathered from global (no weight LDS). Wout/wp computed redundantly.
__global__ __launch_bounds__(256, 8) void gru_actor_kernel(
    const float* __restrict__ x,
    const float* __restrict__ W1, const float* __restrict__ b1,
    const float* __restrict__ W2, const float* __restrict__ b2,
    const float* __restrict__ Wih, const float* __restrict__ bih,
    const float* __restrict__ Whh, const float* __restrict__ bhh,
    const float* __restrict__ Wout, const float* __restrict__ bout,
    float* __restrict__ out)
{
  __shared__ __align__(16) char sm_h[4096];   // [buf][16 rows][128B], XOR-swizzled

  const int t    = threadIdx.x;        // 0..255
  const int q    = t >> 6;             // wave's dim-quarter
  const int l    = t & 63;
  const int lr   = l & 15;
  const int lg   = l >> 4;
  const int rowbase = blockIdx.x * 16;
  const int dimq = q * 16;
  const int swz  = (lr & 7) << 4;
  const int colw = 32 * q + 8 * lg;    // this lane's h-write byte col (pre-XOR)

  // ---------------- layer 1: z1 dims [dimq,dimq+16) = relu(W1T @ xT + b1) ----------------
  f32x4 acc1;
  { float4 bv = *(const float4*)(b1 + dimq + 4 * lg);
    acc1 = (f32x4){bv.x, bv.y, bv.z, bv.w}; }
  {
    const float* xrow = x + (size_t)(rowbase + lr) * 256;
    #pragma unroll
    for (int kb = 0; kb < 8; ++kb){
      int k0 = kb * 32 + lg * 8;
      float4 xa = *(const float4*)(xrow + k0);
      float4 xb = *(const float4*)(xrow + k0 + 4);
      union { unsigned u[4]; short8 s; } bc;
      bc.u[0] = pkbf(xa.x, xa.y); bc.u[1] = pkbf(xa.z, xa.w);
      bc.u[2] = pkbf(xb.x, xb.y); bc.u[3] = pkbf(xb.z, xb.w);
      short8 A = gatherA(W1, 64, k0, dimq + lr, 1.0f);
      acc1 = MFMA16(A, bc.s, acc1);
    }
  }
  // z1 (bf16, relu) -> buf0
  *(uint2*)(sm_h + lr * 128 + (colw ^ swz)) =
      make_uint2(pkbf(fmaxf(acc1[0],0.f), fmaxf(acc1[1],0.f)),
                 pkbf(fmaxf(acc1[2],0.f), fmaxf(acc1[3],0.f)));
  __syncthreads();

  // ---------------- layer 2: h dims [dimq,dimq+16) = relu(W2T @ z1T + b2) ----------------
  f32x2 h2[2];
  {
    f32x4 acc2;
    float4 bv = *(const float4*)(b2 + dimq + 4 * lg);
    acc2 = (f32x4){bv.x, bv.y, bv.z, bv.w};
    #pragma unroll
    for (int kb = 0; kb < 2; ++kb){
      short8 B = *(const short8*)(sm_h + lr * 128 + ((kb * 64 + 16 * lg) ^ swz));
      short8 A = gatherA(W2, 64, kb * 32 + lg * 8, dimq + lr, 1.0f);
      acc2 = MFMA16(A, B, acc2);
    }
    h2[0] = (f32x2){fmaxf(acc2[0],0.f), fmaxf(acc2[1],0.f)};
    h2[1] = (f32x2){fmaxf(acc2[2],0.f), fmaxf(acc2[3],0.f)};
    // h -> buf1 (z1 reads above precede the barrier below; step0 overwrites buf0)
    *(uint2*)(sm_h + 2048 + lr * 128 + (colw ^ swz)) =
        make_uint2(pkbf(h2[0][0], h2[0][1]), pkbf(h2[1][0], h2[1][1]));
  }

  // ---------------- loop-invariant fragments (gathered from global, pre-scaled) ----------------
  short8 Ah[3][2];    // [gate r/u/n][kb]: Whh^T rows for this wave's 16 dims
  #pragma unroll
  for (int g = 0; g < 3; ++g){
    float sc = (g < 2) ? SSC : TSC;
    #pragma unroll
    for (int kb = 0; kb < 2; ++kb)
      Ah[g][kb] = gatherA(Whh, 192, kb * 32 + lg * 8, g * 64 + dimq + lr, sc);
  }
  // augmented k-block (k=64:wp0, 65:wp1, 66:1.0) -> only lg==0 lanes nonzero
  uint2 Ak2p[4] = {};   // [r,u,hn,inn]
  if (lg == 0){
    int dr = dimq + lr, du = 64 + dr, dn = 128 + dr;
    Ak2p[0] = make_uint2(pk(f2bf(SSC*Wih[dr]), f2bf(SSC*Wih[192+dr])),
                         pk(f2bf(SSC*(bih[dr]+bhh[dr])), 0));
    Ak2p[1] = make_uint2(pk(f2bf(SSC*Wih[du]), f2bf(SSC*Wih[192+du])),
                         pk(f2bf(SSC*(bih[du]+bhh[du])), 0));
    Ak2p[2] = make_uint2(0u, pk(f2bf(TSC*bhh[dn]), 0));
    Ak2p[3] = make_uint2(pk(f2bf(TSC*Wih[dn]), f2bf(TSC*Wih[192+dn])),
                         pk(f2bf(TSC*bih[dn]), 0));
  }
  // Wout^T fragments in registers (all waves, redundant wp maintenance)
  short8 AoR[2];
  #pragma unroll
  for (int kb = 0; kb < 2; ++kb){
    short8 f = (short8){0,0,0,0,0,0,0,0};
    if (lr < 2){
      #pragma unroll
      for (int j = 0; j < 8; ++j){
        int k = kb * 32 + lg * 8 + j;
        f[j] = (short)f2bf(SSC * Wout[k * 2 + lr]);
      }
    }
    AoR[kb] = f;
  }
  const float bo0 = SSC * bout[0], bo1 = SSC * bout[1];
  __syncthreads();                                   // h(buf1) ready

  // ---------------- GRU rollout: 1 fused LDS-barrier/step, h double-buffered ----------------
  float wp0 = 0.f, wp1 = 0.f;
  float* outp = out + (size_t)(rowbase + lr) * 100;
  short8 B0 = *(const short8*)(sm_h + 2048 + lr * 128 + ((0  + 16 * lg) ^ swz));
  short8 B1 = *(const short8*)(sm_h + 2048 + lr * 128 + ((64 + 16 * lg) ^ swz));

  #pragma unroll 2
  for (int s = 0; s < TRAJ; ++s){
    char* bufW = sm_h + ((s & 1) << 11);   // step0 writes buf0, step1 buf1, ...
    short8 B2;
    {
      unsigned b2lo = 0u, b2hi = 0u;
      if (lg == 0){ b2lo = pkbf(wp0, wp1); b2hi = 0x00003F80u; }   // f[2] = 1.0bf
      union { unsigned u[4]; short8 sv; } c;
      c.u[0] = b2lo; c.u[1] = b2hi; c.u[2] = 0u; c.u[3] = 0u;
      B2 = c.sv;
    }
    f32x4 aR = (f32x4){0,0,0,0}, aU = (f32x4){0,0,0,0};
    f32x4 aN = (f32x4){0,0,0,0}, aI = (f32x4){0,0,0,0};
    aR = MFMA16(Ah[0][0], B0, aR);
    aR = MFMA16(Ah[0][1], B1, aR);
    aR = MFMA16(mkfrag(Ak2p[0]), B2, aR);
    aU = MFMA16(Ah[1][0], B0, aU);
    aU = MFMA16(Ah[1][1], B1, aU);
    aU = MFMA16(mkfrag(Ak2p[1]), B2, aU);
    aN = MFMA16(Ah[2][0], B0, aN);
    aN = MFMA16(Ah[2][1], B1, aN);
    aN = MFMA16(mkfrag(Ak2p[2]), B2, aN);
    aI = MFMA16(mkfrag(Ak2p[3]), B2, aI);
    f32x2 hA = gru_pair((f32x2){aR[0],aR[1]}, (f32x2){aU[0],aU[1]},
                        (f32x2){aN[0],aN[1]}, (f32x2){aI[0],aI[1]}, h2[0]);
    f32x2 hB = gru_pair((f32x2){aR[2],aR[3]}, (f32x2){aU[2],aU[3]},
                        (f32x2){aN[2],aN[3]}, (f32x2){aI[2],aI[3]}, h2[1]);
    h2[0] = hA; h2[1] = hB;
    *(uint2*)(bufW + lr * 128 + (colw ^ swz)) =
        make_uint2(pkbf(hA[0], hA[1]), pkbf(hB[0], hB[1]));
    BAR();                                     // fused lgkmcnt(0)+s_barrier (LDS-only)
    short8 nB0 = *(const short8*)(bufW + lr * 128 + ((0  + 16 * lg) ^ swz));
    short8 nB1 = *(const short8*)(bufW + lr * 128 + ((64 + 16 * lg) ^ swz));
    f32x4 aD = (f32x4){0,0,0,0};
    if (lg == 0){ aD[0] = bo0; aD[1] = bo1; }
    aD = MFMA16(AoR[0], nB0, aD);
    aD = MFMA16(AoR[1], nB1, aD);
    {
      float ea = EXP2F(aD[0]), eb = EXP2F(aD[1]);
      float da = 1.f + ea, db = 1.f + eb;
      float rp = RCPF(da * db);
      wp0 += db * rp;                          // sigmoid(dx0)
      wp1 += da * rp;                          // sigmoid(dx1)
    }
    if (lg == 0 && q == 0)
      *(float2*)(outp + 2 * s) = make_float2(wp0, wp1);
    B0 = nB0; B1 = nB1;
  }
}

extern "C" void kernel_launch(void* const* d_in, const int* in_sizes, int n_in,
                              void* d_out, int out_size, void* d_ws, size_t ws_size,
                              hipStream_t stream) {
  (void)n_in; (void)out_size; (void)d_ws; (void)ws_size;
  const float* x    = (const float*)d_in[0];
  const float* W1   = (const float*)d_in[1];
  const float* b1   = (const float*)d_in[2];
  const float* W2   = (const float*)d_in[3];
  const float* b2   = (const float*)d_in[4];
  const float* Wih  = (const float*)d_in[5];
  const float* bih  = (const float*)d_in[6];
  const float* Whh  = (const float*)d_in[7];
  const float* bhh  = (const float*)d_in[8];
  const float* Wout = (const float*)d_in[9];
  const float* bout = (const float*)d_in[10];
  float* out = (float*)d_out;

  int nrows = in_sizes[0] / 256;
  int grid  = nrows / 16;                      // one 16-row group per 256-thread block
  gru_actor_kernel<<<dim3(grid), dim3(256), 0, stream>>>(
      x, W1, b1, W2, b2, Wih, bih, Whh, bhh, Wout, bout, out);
}

// Round 10
// 190.655 us; speedup vs baseline: 2.1229x; 2.1229x over previous
//
#include <hip/hip_runtime.h>
#include <hip/hip_bf16.h>

#define TRAJ 50

typedef __attribute__((ext_vector_type(8))) short short8;
typedef __attribute__((ext_vector_type(4))) float f32x4;
typedef __attribute__((ext_vector_type(2))) float f32x2;

#if defined(__has_builtin)
#if __has_builtin(__builtin_amdgcn_exp2f)
#define EXP2F(x) __builtin_amdgcn_exp2f(x)
#else
#define EXP2F(x) exp2f(x)
#endif
#if __has_builtin(__builtin_amdgcn_rcpf)
#define RCPF(x) __builtin_amdgcn_rcpf(x)
#else
#define RCPF(x) (1.0f/(x))
#endif
#else
#define EXP2F(x) exp2f(x)
#define RCPF(x) (1.0f/(x))
#endif

// LDS-only fused barrier (verified rounds 6/8): no schedulable gap between the
// lgkm wait and s_barrier; does NOT drain global stores (vmcnt).
#define BAR() asm volatile("s_waitcnt lgkmcnt(0)\n\ts_barrier" ::: "memory")

__device__ __forceinline__ unsigned short f2bf(float f){
  union { float f; unsigned u; } v; v.f = f;
  unsigned u = v.u;
  u += 0x7FFFu + ((u >> 16) & 1u);   // RNE
  return (unsigned short)(u >> 16);
}
__device__ __forceinline__ unsigned pk(unsigned short a, unsigned short b){
  return (unsigned)a | ((unsigned)b << 16);
}
__device__ __forceinline__ unsigned pkbf(float a, float b){
  union { __hip_bfloat162 h; unsigned u; } c;
  c.h = __float22bfloat162_rn(make_float2(a, b));   // v_cvt_pk_bf16_f32
  return c.u;
}
__device__ __forceinline__ short8 mkfrag(uint2 v){
  union { unsigned u[4]; short8 s; } c;
  c.u[0] = v.x; c.u[1] = v.y; c.u[2] = 0u; c.u[3] = 0u;
  return c.s;
}

#define MFMA16(A,B,C) __builtin_amdgcn_mfma_f32_16x16x32_bf16((A),(B),(C),0,0,0)

#define SSC (-1.44269504f)   // sigmoid scale: sigma(x) = 1/(1+2^(SSC*x))
#define TSC ( 2.88539008f)   // tanh scale:   tanh(y)  = 1-2/(1+2^(TSC*y))

__device__ __forceinline__ f32x2 exp2v(f32x2 v){ return (f32x2){EXP2F(v[0]), EXP2F(v[1])}; }
__device__ __forceinline__ f32x2 rcpv (f32x2 v){ return (f32x2){RCPF(v[0]), RCPF(v[1])}; }

// per element pair: r/u sigmoids share one rcp; tanh via exp2+rcp.
// (round-2/6/8 math, verified absmax 0.125)
__device__ __forceinline__ f32x2 gru_pair(f32x2 r_, f32x2 u_, f32x2 n_, f32x2 i_, f32x2 hp){
  const f32x2 one = (f32x2){1.f, 1.f};
  f32x2 d1 = exp2v(r_) + one;
  f32x2 d2 = exp2v(u_) + one;
  f32x2 rp = rcpv(d1 * d2);
  f32x2 rv = d2 * rp;                               // sigma(arg_r)
  f32x2 uv = d1 * rp;                               // sigma(arg_u)
  f32x2 y  = __builtin_elementwise_fma(rv, n_, i_); // TSC*(inn + r*hn)
  f32x2 nv = one - 2.f * rcpv(exp2v(y) + one);      // tanh
  return __builtin_elementwise_fma(uv, hp - nv, nv);
}

// gather an A fragment directly from a global row-major [K][N] f32 matrix:
// frag elements = scale * M[k0+j][i], j=0..7 (k0 = kb*32 + lg*8), i = row index.
// Proven (r7/r8): lane holds k-elems lg*8..lg*8+7 of its 32-k block.
__device__ __forceinline__ short8 gatherA(const float* __restrict__ M, int N,
                                          int k0, int i, float scale){
  const float* qp = M + (size_t)k0 * N + i;
  union { unsigned u[4]; short8 s; } c;
  #pragma unroll
  for (int j = 0; j < 4; ++j){
    float a = qp[(2*j  ) * N];
    float b = qp[(2*j+1) * N];
    c.u[j] = pk(f2bf(scale * a), f2bf(scale * b));
  }
  return c.s;
}

// DECORRELATED QUAD-SPLIT (round-9 structure, launch bound relaxed 8->6 so the
// loop-invariant fragments stay in registers: r9's bound forced VGPR=32 and the
// compiler re-gathered Whh from global EVERY STEP -> 858MB fetch, memory-bound).
// Block = 256 threads = 4 waves = ONE 16-row group; wave q owns dims [16q,16q+16).
__global__ __launch_bounds__(256, 6) void gru_actor_kernel(
    const float* __restrict__ x,
    const float* __restrict__ W1, const float* __restrict__ b1,
    const float* __restrict__ W2, const float* __restrict__ b2,
    const float* __restrict__ Wih, const float* __restrict__ bih,
    const float* __restrict__ Whh, const float* __restrict__ bhh,
    const float* __restrict__ Wout, const float* __restrict__ bout,
    float* __restrict__ out)
{
  __shared__ __align__(16) char sm_h[4096];   // [buf][16 rows][128B], XOR-swizzled

  const int t    = threadIdx.x;        // 0..255
  const int q    = t >> 6;             // wave's dim-quarter
  const int l    = t & 63;
  const int lr   = l & 15;
  const int lg   = l >> 4;
  const int rowbase = blockIdx.x * 16;
  const int dimq = q * 16;
  const int swz  = (lr & 7) << 4;
  const int colw = 32 * q + 8 * lg;    // this lane's h-write byte col (pre-XOR)

  // ---------------- layer 1: z1 dims [dimq,dimq+16) = relu(W1T @ xT + b1) ----------------
  f32x4 acc1;
  { float4 bv = *(const float4*)(b1 + dimq + 4 * lg);
    acc1 = (f32x4){bv.x, bv.y, bv.z, bv.w}; }
  {
    const float* xrow = x + (size_t)(rowbase + lr) * 256;
    #pragma unroll
    for (int kb = 0; kb < 8; ++kb){
      int k0 = kb * 32 + lg * 8;
      float4 xa = *(const float4*)(xrow + k0);
      float4 xb = *(const float4*)(xrow + k0 + 4);
      union { unsigned u[4]; short8 s; } bc;
      bc.u[0] = pkbf(xa.x, xa.y); bc.u[1] = pkbf(xa.z, xa.w);
      bc.u[2] = pkbf(xb.x, xb.y); bc.u[3] = pkbf(xb.z, xb.w);
      short8 A = gatherA(W1, 64, k0, dimq + lr, 1.0f);
      acc1 = MFMA16(A, bc.s, acc1);
    }
  }
  // z1 (bf16, relu) -> buf0
  *(uint2*)(sm_h + lr * 128 + (colw ^ swz)) =
      make_uint2(pkbf(fmaxf(acc1[0],0.f), fmaxf(acc1[1],0.f)),
                 pkbf(fmaxf(acc1[2],0.f), fmaxf(acc1[3],0.f)));
  __syncthreads();

  // ---------------- layer 2: h dims [dimq,dimq+16) = relu(W2T @ z1T + b2) ----------------
  f32x2 h2[2];
  {
    f32x4 acc2;
    float4 bv = *(const float4*)(b2 + dimq + 4 * lg);
    acc2 = (f32x4){bv.x, bv.y, bv.z, bv.w};
    #pragma unroll
    for (int kb = 0; kb < 2; ++kb){
      short8 B = *(const short8*)(sm_h + lr * 128 + ((kb * 64 + 16 * lg) ^ swz));
      short8 A = gatherA(W2, 64, kb * 32 + lg * 8, dimq + lr, 1.0f);
      acc2 = MFMA16(A, B, acc2);
    }
    h2[0] = (f32x2){fmaxf(acc2[0],0.f), fmaxf(acc2[1],0.f)};
    h2[1] = (f32x2){fmaxf(acc2[2],0.f), fmaxf(acc2[3],0.f)};
    // h -> buf1 (z1 reads above precede the barrier below; step0 overwrites buf0)
    *(uint2*)(sm_h + 2048 + lr * 128 + (colw ^ swz)) =
        make_uint2(pkbf(h2[0][0], h2[0][1]), pkbf(h2[1][0], h2[1][1]));
  }

  // ---------------- loop-invariant fragments (gathered from global, pre-scaled) ----------------
  short8 Ah[3][2];    // [gate r/u/n][kb]: Whh^T rows for this wave's 16 dims
  #pragma unroll
  for (int g = 0; g < 3; ++g){
    float sc = (g < 2) ? SSC : TSC;
    #pragma unroll
    for (int kb = 0; kb < 2; ++kb)
      Ah[g][kb] = gatherA(Whh, 192, kb * 32 + lg * 8, g * 64 + dimq + lr, sc);
  }
  // augmented k-block (k=64:wp0, 65:wp1, 66:1.0) -> only lg==0 lanes nonzero
  uint2 Ak2p[4] = {};   // [r,u,hn,inn]
  if (lg == 0){
    int dr = dimq + lr, du = 64 + dr, dn = 128 + dr;
    Ak2p[0] = make_uint2(pk(f2bf(SSC*Wih[dr]), f2bf(SSC*Wih[192+dr])),
                         pk(f2bf(SSC*(bih[dr]+bhh[dr])), 0));
    Ak2p[1] = make_uint2(pk(f2bf(SSC*Wih[du]), f2bf(SSC*Wih[192+du])),
                         pk(f2bf(SSC*(bih[du]+bhh[du])), 0));
    Ak2p[2] = make_uint2(0u, pk(f2bf(TSC*bhh[dn]), 0));
    Ak2p[3] = make_uint2(pk(f2bf(TSC*Wih[dn]), f2bf(TSC*Wih[192+dn])),
                         pk(f2bf(TSC*bih[dn]), 0));
  }
  // Wout^T fragments in registers (all waves, redundant wp maintenance)
  short8 AoR[2];
  #pragma unroll
  for (int kb = 0; kb < 2; ++kb){
    short8 f = (short8){0,0,0,0,0,0,0,0};
    if (lr < 2){
      #pragma unroll
      for (int j = 0; j < 8; ++j){
        int k = kb * 32 + lg * 8 + j;
        f[j] = (short)f2bf(SSC * Wout[k * 2 + lr]);
      }
    }
    AoR[kb] = f;
  }
  const float bo0 = SSC * bout[0], bo1 = SSC * bout[1];
  __syncthreads();                                   // h(buf1) ready

  // ---------------- GRU rollout: 1 fused LDS-barrier/step, h double-buffered ----------------
  float wp0 = 0.f, wp1 = 0.f;
  float* outp = out + (size_t)(rowbase + lr) * 100;
  short8 B0 = *(const short8*)(sm_h + 2048 + lr * 128 + ((0  + 16 * lg) ^ swz));
  short8 B1 = *(const short8*)(sm_h + 2048 + lr * 128 + ((64 + 16 * lg) ^ swz));

  #pragma unroll 2
  for (int s = 0; s < TRAJ; ++s){
    char* bufW = sm_h + ((s & 1) << 11);   // step0 writes buf0, step1 buf1, ...
    short8 B2;
    {
      unsigned b2lo = 0u, b2hi = 0u;
      if (lg == 0){ b2lo = pkbf(wp0, wp1); b2hi = 0x00003F80u; }   // f[2] = 1.0bf
      union { unsigned u[4]; short8 sv; } c;
      c.u[0] = b2lo; c.u[1] = b2hi; c.u[2] = 0u; c.u[3] = 0u;
      B2 = c.sv;
    }
    f32x4 aR = (f32x4){0,0,0,0}, aU = (f32x4){0,0,0,0};
    f32x4 aN = (f32x4){0,0,0,0}, aI = (f32x4){0,0,0,0};
    aR = MFMA16(Ah[0][0], B0, aR);
    aR = MFMA16(Ah[0][1], B1, aR);
    aR = MFMA16(mkfrag(Ak2p[0]), B2, aR);
    aU = MFMA16(Ah[1][0], B0, aU);
    aU = MFMA16(Ah[1][1], B1, aU);
    aU = MFMA16(mkfrag(Ak2p[1]), B2, aU);
    aN = MFMA16(Ah[2][0], B0, aN);
    aN = MFMA16(Ah[2][1], B1, aN);
    aN = MFMA16(mkfrag(Ak2p[2]), B2, aN);
    aI = MFMA16(mkfrag(Ak2p[3]), B2, aI);
    f32x2 hA = gru_pair((f32x2){aR[0],aR[1]}, (f32x2){aU[0],aU[1]},
                        (f32x2){aN[0],aN[1]}, (f32x2){aI[0],aI[1]}, h2[0]);
    f32x2 hB = gru_pair((f32x2){aR[2],aR[3]}, (f32x2){aU[2],aU[3]},
                        (f32x2){aN[2],aN[3]}, (f32x2){aI[2],aI[3]}, h2[1]);
    h2[0] = hA; h2[1] = hB;
    *(uint2*)(bufW + lr * 128 + (colw ^ swz)) =
        make_uint2(pkbf(hA[0], hA[1]), pkbf(hB[0], hB[1]));
    BAR();                                     // fused lgkmcnt(0)+s_barrier (LDS-only)
    short8 nB0 = *(const short8*)(bufW + lr * 128 + ((0  + 16 * lg) ^ swz));
    short8 nB1 = *(const short8*)(bufW + lr * 128 + ((64 + 16 * lg) ^ swz));
    f32x4 aD = (f32x4){0,0,0,0};
    if (lg == 0){ aD[0] = bo0; aD[1] = bo1; }
    aD = MFMA16(AoR[0], nB0, aD);
    aD = MFMA16(AoR[1], nB1, aD);
    {
      float ea = EXP2F(aD[0]), eb = EXP2F(aD[1]);
      float da = 1.f + ea, db = 1.f + eb;
      float rp = RCPF(da * db);
      wp0 += db * rp;                          // sigmoid(dx0)
      wp1 += da * rp;                          // sigmoid(dx1)
    }
    if (lg == 0 && q == 0)
      *(float2*)(outp + 2 * s) = make_float2(wp0, wp1);
    B0 = nB0; B1 = nB1;
  }
}

extern "C" void kernel_launch(void* const* d_in, const int* in_sizes, int n_in,
                              void* d_out, int out_size, void* d_ws, size_t ws_size,
                              hipStream_t stream) {
  (void)n_in; (void)out_size; (void)d_ws; (void)ws_size;
  const float* x    = (const float*)d_in[0];
  const float* W1   = (const float*)d_in[1];
  const float* b1   = (const float*)d_in[2];
  const float* W2   = (const float*)d_in[3];
  const float* b2   = (const float*)d_in[4];
  const float* Wih  = (const float*)d_in[5];
  const float* bih  = (const float*)d_in[6];
  const float* Whh  = (const float*)d_in[7];
  const float* bhh  = (const float*)d_in[8];
  const float* Wout = (const float*)d_in[9];
  const float* bout = (const float*)d_in[10];
  float* out = (float*)d_out;

  int nrows = in_sizes[0] / 256;
  int grid  = nrows / 16;                      // one 16-row group per 256-thread block
  gru_actor_kernel<<<dim3(grid), dim3(256), 0, stream>>>(
      x, W1, b1, W2, b2, Wih, bih, Whh, bhh, Wout, bout, out);
}

// Round 11
// 110.943 us; speedup vs baseline: 3.6482x; 1.7185x over previous
//
#include <hip/hip_runtime.h>
#include <hip/hip_bf16.h>

#define TRAJ 50

typedef __attribute__((ext_vector_type(8))) short short8;
typedef __attribute__((ext_vector_type(4))) float f32x4;
typedef __attribute__((ext_vector_type(2))) float f32x2;

#if defined(__has_builtin)
#if __has_builtin(__builtin_amdgcn_exp2f)
#define EXP2F(x) __builtin_amdgcn_exp2f(x)
#else
#define EXP2F(x) exp2f(x)
#endif
#if __has_builtin(__builtin_amdgcn_rcpf)
#define RCPF(x) __builtin_amdgcn_rcpf(x)
#else
#define RCPF(x) (1.0f/(x))
#endif
#else
#define EXP2F(x) exp2f(x)
#define RCPF(x) (1.0f/(x))
#endif

// LDS-only fused barrier (verified rounds 6/8): no schedulable gap between the
// lgkm wait and s_barrier; does NOT drain global stores (vmcnt).
#define BAR() asm volatile("s_waitcnt lgkmcnt(0)\n\ts_barrier" ::: "memory")

__device__ __forceinline__ unsigned short f2bf(float f){
  union { float f; unsigned u; } v; v.f = f;
  unsigned u = v.u;
  u += 0x7FFFu + ((u >> 16) & 1u);   // RNE
  return (unsigned short)(u >> 16);
}
__device__ __forceinline__ unsigned pk(unsigned short a, unsigned short b){
  return (unsigned)a | ((unsigned)b << 16);
}
__device__ __forceinline__ unsigned pkbf(float a, float b){
  union { __hip_bfloat162 h; unsigned u; } c;
  c.h = __float22bfloat162_rn(make_float2(a, b));   // v_cvt_pk_bf16_f32
  return c.u;
}
__device__ __forceinline__ short8 mkfrag(uint2 v){
  union { unsigned u[4]; short8 s; } c;
  c.u[0] = v.x; c.u[1] = v.y; c.u[2] = 0u; c.u[3] = 0u;
  return c.s;
}

#define MFMA16(A,B,C) __builtin_amdgcn_mfma_f32_16x16x32_bf16((A),(B),(C),0,0,0)

#define SSC (-1.44269504f)   // sigmoid scale: sigma(x) = 1/(1+2^(SSC*x))
#define TSC ( 2.88539008f)   // tanh scale:   tanh(y)  = 1-2/(1+2^(TSC*y))

__device__ __forceinline__ f32x2 exp2v(f32x2 v){ return (f32x2){EXP2F(v[0]), EXP2F(v[1])}; }
__device__ __forceinline__ f32x2 rcpv (f32x2 v){ return (f32x2){RCPF(v[0]), RCPF(v[1])}; }

// per element pair: r/u sigmoids share one rcp; tanh via exp2+rcp.
// (round-2/6/8 math, verified absmax 0.125)
__device__ __forceinline__ f32x2 gru_pair(f32x2 r_, f32x2 u_, f32x2 n_, f32x2 i_, f32x2 hp){
  const f32x2 one = (f32x2){1.f, 1.f};
  f32x2 d1 = exp2v(r_) + one;
  f32x2 d2 = exp2v(u_) + one;
  f32x2 rp = rcpv(d1 * d2);
  f32x2 rv = d2 * rp;                               // sigma(arg_r)
  f32x2 uv = d1 * rp;                               // sigma(arg_u)
  f32x2 y  = __builtin_elementwise_fma(rv, n_, i_); // TSC*(inn + r*hn)
  f32x2 nv = one - 2.f * rcpv(exp2v(y) + one);      // tanh
  return __builtin_elementwise_fma(uv, hp - nv, nv);
}

// gather an A fragment directly from a global row-major [K][N] f32 matrix:
// frag elements = scale * M[k0+j][i], j=0..7 (k0 = kb*32 + lg*8), i = row index.
// Proven (r7/r8): lane holds k-elems lg*8..lg*8+7 of its 32-k block.
__device__ __forceinline__ short8 gatherA(const float* __restrict__ M, int N,
                                          int k0, int i, float scale){
  const float* qp = M + (size_t)k0 * N + i;
  union { unsigned u[4]; short8 s; } c;
  #pragma unroll
  for (int j = 0; j < 4; ++j){
    float a = qp[(2*j  ) * N];
    float b = qp[(2*j+1) * N];
    c.u[j] = pk(f2bf(scale * a), f2bf(scale * b));
  }
  return c.s;
}

// DECORRELATED QUAD-SPLIT (round-9/10 structure, launch bound relaxed to (256,4):
// cap 128 VGPR. r9's (256,8) forced 32 VGPR -> per-step Whh remat (858MB fetch);
// r10's (256,6) forced 40 VGPR -> scratch spill (120MB write). Under cap 128 this
// body compiled spill-free at 48 VGPR (r8). Block = 256 thr = 4 waves = ONE
// 16-row group; wave q owns dims [16q,16q+16).
__global__ __launch_bounds__(256, 4) void gru_actor_kernel(
    const float* __restrict__ x,
    const float* __restrict__ W1, const float* __restrict__ b1,
    const float* __restrict__ W2, const float* __restrict__ b2,
    const float* __restrict__ Wih, const float* __restrict__ bih,
    const float* __restrict__ Whh, const float* __restrict__ bhh,
    const float* __restrict__ Wout, const float* __restrict__ bout,
    float* __restrict__ out)
{
  __shared__ __align__(16) char sm_h[4096];   // [buf][16 rows][128B], XOR-swizzled

  const int t    = threadIdx.x;        // 0..255
  const int q    = t >> 6;             // wave's dim-quarter
  const int l    = t & 63;
  const int lr   = l & 15;
  const int lg   = l >> 4;
  const int rowbase = blockIdx.x * 16;
  const int dimq = q * 16;
  const int swz  = (lr & 7) << 4;
  const int colw = 32 * q + 8 * lg;    // this lane's h-write byte col (pre-XOR)

  // ---------------- layer 1: z1 dims [dimq,dimq+16) = relu(W1T @ xT + b1) ----------------
  f32x4 acc1;
  { float4 bv = *(const float4*)(b1 + dimq + 4 * lg);
    acc1 = (f32x4){bv.x, bv.y, bv.z, bv.w}; }
  {
    const float* xrow = x + (size_t)(rowbase + lr) * 256;
    #pragma unroll
    for (int kb = 0; kb < 8; ++kb){
      int k0 = kb * 32 + lg * 8;
      float4 xa = *(const float4*)(xrow + k0);
      float4 xb = *(const float4*)(xrow + k0 + 4);
      union { unsigned u[4]; short8 s; } bc;
      bc.u[0] = pkbf(xa.x, xa.y); bc.u[1] = pkbf(xa.z, xa.w);
      bc.u[2] = pkbf(xb.x, xb.y); bc.u[3] = pkbf(xb.z, xb.w);
      short8 A = gatherA(W1, 64, k0, dimq + lr, 1.0f);
      acc1 = MFMA16(A, bc.s, acc1);
    }
  }
  // z1 (bf16, relu) -> buf0
  *(uint2*)(sm_h + lr * 128 + (colw ^ swz)) =
      make_uint2(pkbf(fmaxf(acc1[0],0.f), fmaxf(acc1[1],0.f)),
                 pkbf(fmaxf(acc1[2],0.f), fmaxf(acc1[3],0.f)));
  __syncthreads();

  // ---------------- layer 2: h dims [dimq,dimq+16) = relu(W2T @ z1T + b2) ----------------
  f32x2 h2[2];
  {
    f32x4 acc2;
    float4 bv = *(const float4*)(b2 + dimq + 4 * lg);
    acc2 = (f32x4){bv.x, bv.y, bv.z, bv.w};
    #pragma unroll
    for (int kb = 0; kb < 2; ++kb){
      short8 B = *(const short8*)(sm_h + lr * 128 + ((kb * 64 + 16 * lg) ^ swz));
      short8 A = gatherA(W2, 64, kb * 32 + lg * 8, dimq + lr, 1.0f);
      acc2 = MFMA16(A, B, acc2);
    }
    h2[0] = (f32x2){fmaxf(acc2[0],0.f), fmaxf(acc2[1],0.f)};
    h2[1] = (f32x2){fmaxf(acc2[2],0.f), fmaxf(acc2[3],0.f)};
    // h -> buf1 (z1 reads above precede the barrier below; step0 overwrites buf0)
    *(uint2*)(sm_h + 2048 + lr * 128 + (colw ^ swz)) =
        make_uint2(pkbf(h2[0][0], h2[0][1]), pkbf(h2[1][0], h2[1][1]));
  }

  // ---------------- loop-invariant fragments (gathered from global, pre-scaled) ----------------
  short8 Ah[3][2];    // [gate r/u/n][kb]: Whh^T rows for this wave's 16 dims
  #pragma unroll
  for (int g = 0; g < 3; ++g){
    float sc = (g < 2) ? SSC : TSC;
    #pragma unroll
    for (int kb = 0; kb < 2; ++kb)
      Ah[g][kb] = gatherA(Whh, 192, kb * 32 + lg * 8, g * 64 + dimq + lr, sc);
  }
  // augmented k-block (k=64:wp0, 65:wp1, 66:1.0) -> only lg==0 lanes nonzero
  uint2 Ak2p[4] = {};   // [r,u,hn,inn]
  if (lg == 0){
    int dr = dimq + lr, du = 64 + dr, dn = 128 + dr;
    Ak2p[0] = make_uint2(pk(f2bf(SSC*Wih[dr]), f2bf(SSC*Wih[192+dr])),
                         pk(f2bf(SSC*(bih[dr]+bhh[dr])), 0));
    Ak2p[1] = make_uint2(pk(f2bf(SSC*Wih[du]), f2bf(SSC*Wih[192+du])),
                         pk(f2bf(SSC*(bih[du]+bhh[du])), 0));
    Ak2p[2] = make_uint2(0u, pk(f2bf(TSC*bhh[dn]), 0));
    Ak2p[3] = make_uint2(pk(f2bf(TSC*Wih[dn]), f2bf(TSC*Wih[192+dn])),
                         pk(f2bf(TSC*bih[dn]), 0));
  }
  // Wout^T fragments in registers (all waves, redundant wp maintenance)
  short8 AoR[2];
  #pragma unroll
  for (int kb = 0; kb < 2; ++kb){
    short8 f = (short8){0,0,0,0,0,0,0,0};
    if (lr < 2){
      #pragma unroll
      for (int j = 0; j < 8; ++j){
        int k = kb * 32 + lg * 8 + j;
        f[j] = (short)f2bf(SSC * Wout[k * 2 + lr]);
      }
    }
    AoR[kb] = f;
  }
  const float bo0 = SSC * bout[0], bo1 = SSC * bout[1];
  __syncthreads();                                   // h(buf1) ready

  // ---------------- GRU rollout: 1 fused LDS-barrier/step, h double-buffered ----------------
  float wp0 = 0.f, wp1 = 0.f;
  float* outp = out + (size_t)(rowbase + lr) * 100;
  short8 B0 = *(const short8*)(sm_h + 2048 + lr * 128 + ((0  + 16 * lg) ^ swz));
  short8 B1 = *(const short8*)(sm_h + 2048 + lr * 128 + ((64 + 16 * lg) ^ swz));

  #pragma unroll 2
  for (int s = 0; s < TRAJ; ++s){
    char* bufW = sm_h + ((s & 1) << 11);   // step0 writes buf0, step1 buf1, ...
    short8 B2;
    {
      unsigned b2lo = 0u, b2hi = 0u;
      if (lg == 0){ b2lo = pkbf(wp0, wp1); b2hi = 0x00003F80u; }   // f[2] = 1.0bf
      union { unsigned u[4]; short8 sv; } c;
      c.u[0] = b2lo; c.u[1] = b2hi; c.u[2] = 0u; c.u[3] = 0u;
      B2 = c.sv;
    }
    f32x4 aR = (f32x4){0,0,0,0}, aU = (f32x4){0,0,0,0};
    f32x4 aN = (f32x4){0,0,0,0}, aI = (f32x4){0,0,0,0};
    aR = MFMA16(Ah[0][0], B0, aR);
    aR = MFMA16(Ah[0][1], B1, aR);
    aR = MFMA16(mkfrag(Ak2p[0]), B2, aR);
    aU = MFMA16(Ah[1][0], B0, aU);
    aU = MFMA16(Ah[1][1], B1, aU);
    aU = MFMA16(mkfrag(Ak2p[1]), B2, aU);
    aN = MFMA16(Ah[2][0], B0, aN);
    aN = MFMA16(Ah[2][1], B1, aN);
    aN = MFMA16(mkfrag(Ak2p[2]), B2, aN);
    aI = MFMA16(mkfrag(Ak2p[3]), B2, aI);
    f32x2 hA = gru_pair((f32x2){aR[0],aR[1]}, (f32x2){aU[0],aU[1]},
                        (f32x2){aN[0],aN[1]}, (f32x2){aI[0],aI[1]}, h2[0]);
    f32x2 hB = gru_pair((f32x2){aR[2],aR[3]}, (f32x2){aU[2],aU[3]},
                        (f32x2){aN[2],aN[3]}, (f32x2){aI[2],aI[3]}, h2[1]);
    h2[0] = hA; h2[1] = hB;
    *(uint2*)(bufW + lr * 128 + (colw ^ swz)) =
        make_uint2(pkbf(hA[0], hA[1]), pkbf(hB[0], hB[1]));
    BAR();                                     // fused lgkmcnt(0)+s_barrier (LDS-only)
    short8 nB0 = *(const short8*)(bufW + lr * 128 + ((0  + 16 * lg) ^ swz));
    short8 nB1 = *(const short8*)(bufW + lr * 128 + ((64 + 16 * lg) ^ swz));
    f32x4 aD = (f32x4){0,0,0,0};
    if (lg == 0){ aD[0] = bo0; aD[1] = bo1; }
    aD = MFMA16(AoR[0], nB0, aD);
    aD = MFMA16(AoR[1], nB1, aD);
    {
      float ea = EXP2F(aD[0]), eb = EXP2F(aD[1]);
      float da = 1.f + ea, db = 1.f + eb;
      float rp = RCPF(da * db);
      wp0 += db * rp;                          // sigmoid(dx0)
      wp1 += da * rp;                          // sigmoid(dx1)
    }
    if (lg == 0 && q == 0)
      *(float2*)(outp + 2 * s) = make_float2(wp0, wp1);
    B0 = nB0; B1 = nB1;
  }
}

extern "C" void kernel_launch(void* const* d_in, const int* in_sizes, int n_in,
                              void* d_out, int out_size, void* d_ws, size_t ws_size,
                              hipStream_t stream) {
  (void)n_in; (void)out_size; (void)d_ws; (void)ws_size;
  const float* x    = (const float*)d_in[0];
  const float* W1   = (const float*)d_in[1];
  const float* b1   = (const float*)d_in[2];
  const float* W2   = (const float*)d_in[3];
  const float* b2   = (const float*)d_in[4];
  const float* Wih  = (const float*)d_in[5];
  const float* bih  = (const float*)d_in[6];
  const float* Whh  = (const float*)d_in[7];
  const float* bhh  = (const float*)d_in[8];
  const float* Wout = (const float*)d_in[9];
  const float* bout = (const float*)d_in[10];
  float* out = (float*)d_out;

  int nrows = in_sizes[0] / 256;
  int grid  = nrows / 16;                      // one 16-row group per 256-thread block
  gru_actor_kernel<<<dim3(grid), dim3(256), 0, stream>>>(
      x, W1, b1, W2, b2, Wih, bih, Whh, bhh, Wout, bout, out);
}